// Round 4
// baseline (219.759 us; speedup 1.0000x reference)
//
#include <hip/hip_runtime.h>
#include <hip/hip_bf16.h>

#define NB 16
#define NS 2048
#define NE 256
#define NOUT 256
#define CAP 49152  // correction-record capacity (diag = 32768)

typedef __attribute__((ext_vector_type(4))) float f32x4;
typedef __attribute__((ext_vector_type(8))) short s16x8;
typedef __attribute__((ext_vector_type(4))) short s16x4;
typedef unsigned int u32;

__device__ __forceinline__ short bf16rn(float f) {
  unsigned u = __builtin_bit_cast(unsigned, f);
  u += 0x7FFFu + ((u >> 16) & 1u);
  return (short)(u >> 16);
}
__device__ __forceinline__ float bf16f(short s) {
  unsigned u = ((unsigned)(unsigned short)s) << 16;
  return __builtin_bit_cast(float, u);
}
__device__ __forceinline__ void gld_lds16(const void* g, void* l) {
  __builtin_amdgcn_global_load_lds(
      (const __attribute__((address_space(1))) u32*)g,
      (__attribute__((address_space(3))) u32*)l, 16, 0, 0);
}

// ---------- prep: x f32 -> xbf bf16 + sq ----------
__global__ __launch_bounds__(256) void prep_kernel(const float* __restrict__ x,
                                                   short* __restrict__ xbf,
                                                   float* __restrict__ sq) {
  int row = blockIdx.x * 4 + (threadIdx.x >> 6);
  int lane = threadIdx.x & 63;
  f32x4 v = *(const f32x4*)(x + (size_t)row * NE + lane * 4);
  s16x4 p;
  p[0] = bf16rn(v.x); p[1] = bf16rn(v.y); p[2] = bf16rn(v.z); p[3] = bf16rn(v.w);
  *(s16x4*)(xbf + (size_t)row * NE + lane * 4) = p;
  float s = v.x * v.x + v.y * v.y + v.z * v.z + v.w * v.w;
#pragma unroll
  for (int off = 32; off; off >>= 1) s += __shfl_xor(s, off);
  if (lane == 0) sq[row] = s;
}

// ---------- gram: row-strip blocks, A in registers, B-chunk dbuf ----------
// grid 512 = b(16) x strip(16) x half(2). rpart[(b*2+half)*NS + row] = partial
// row sum over this half's 1024 cols. Non-skip elements appended to records.
__global__ __launch_bounds__(256, 2) void gram(
    const short* __restrict__ xbf, const float* __restrict__ sqg,
    const float* __restrict__ alpha_p, float* __restrict__ rpart,
    u32* __restrict__ counter, u32* __restrict__ records) {
  __shared__ char lds[65536];  // A-stage 64KB, then B dbuf 2x32KB
  __shared__ float sqall[NS];  // whole batch sq (8KB)

  const int tid = threadIdx.x;
  const int lane = tid & 63;
  const int wid = tid >> 6;
  const int lrow = lane & 15, lq = lane >> 4;

  // XCD-chunked: 512 = 8 * 64 -> 2 batches per XCD (B strip L2-resident)
  const int nbid = (blockIdx.x & 7) * 64 + (blockIdx.x >> 3);
  const int b = nbid >> 5;
  const int strip = (nbid & 31) >> 1;
  const int half = nbid & 1;
  const int rowbase = strip * 128;
  const char* xc = (const char*)(xbf + (size_t)b * NS * NE);
  const float alpha = alpha_p[0];
  const float nal = -alpha;
  const float thresh = 17.328680f / alpha;  // 25 ln2 / alpha

  // stage whole-batch sq into LDS
  {
    const f32x4* s4 = (const f32x4*)(sqg + b * NS);
    *(f32x4*)&sqall[tid * 8] = s4[tid * 2];
    *(f32x4*)&sqall[tid * 8 + 4] = s4[tid * 2 + 1];
  }

  // stage A strip [128 rows][512B] into lds (inverse-swizzled source)
#pragma unroll
  for (int c = 0; c < 16; ++c) {
    int rl = wid * 32 + c * 2 + (lane >> 5);
    int inner = ((lane & 31) * 16) ^ ((rl & 7) << 4);
    gld_lds16(xc + (size_t)(rowbase + rl) * 512 + inner,
              (char*)lds + wid * 16384 + c * 1024 + lane * 16);
  }
  __syncthreads();

  // A fragments to registers: af[m][kstep 0..7]
  s16x8 af[2][8];
#pragma unroll
  for (int m = 0; m < 2; ++m) {
    int row = wid * 32 + m * 16 + lrow;
#pragma unroll
    for (int ks = 0; ks < 8; ++ks)
      af[m][ks] = *(const s16x8*)((const char*)lds + row * 512 +
                                  ((ks * 64 + lq * 16) ^ ((row & 7) << 4)));
  }
  float rr[2][4];
  float minrr = 3.4e38f;
#pragma unroll
  for (int m = 0; m < 2; ++m)
#pragma unroll
    for (int j = 0; j < 4; ++j) {
      rr[m][j] = sqall[rowbase + wid * 32 + m * 16 + lq * 4 + j];
      minrr = fminf(minrr, rr[m][j]);
    }
  __syncthreads();  // all A reads done before B staging overwrites

  // B chunk staging: chunk ci = (bt_local<<1)|kh ; 128 cols x 128 k = 32KB
  auto stageB = [&](int ci, char* buf) {
    int bt = half * 8 + (ci >> 1);
    int kh = ci & 1;
    const char* base = xc + (size_t)(bt * 128) * 512 + kh * 256;
#pragma unroll
    for (int c = 0; c < 8; ++c) {
      int cl = wid * 32 + c * 4 + (lane >> 4);
      int inner = ((lane & 15) * 16) ^ ((cl & 7) << 4);
      gld_lds16(base + (size_t)cl * 512 + inner,
                buf + wid * 8192 + c * 1024 + lane * 16);
    }
  };

  f32x4 acc[2][8];
#pragma unroll
  for (int m = 0; m < 2; ++m)
#pragma unroll
    for (int n = 0; n < 8; ++n) acc[m][n] = (f32x4){0.f, 0.f, 0.f, 0.f};
  float prs[2][4] = {{0.f, 0.f, 0.f, 0.f}, {0.f, 0.f, 0.f, 0.f}};

  stageB(0, (char*)lds);
  __syncthreads();

#pragma unroll 1
  for (int ci = 0; ci < 16; ++ci) {
    char* buf = (char*)lds + (ci & 1) * 32768;
    if (ci + 1 < 16) stageB(ci + 1, (char*)lds + ((ci + 1) & 1) * 32768);

    const int kh = ci & 1;
#pragma unroll
    for (int ks = 0; ks < 4; ++ks) {
      s16x8 bv[8];
#pragma unroll
      for (int n = 0; n < 8; ++n) {
        int col = n * 16 + lrow;
        bv[n] = *(const s16x8*)(buf + col * 256 +
                                ((ks * 64 + lq * 16) ^ ((col & 7) << 4)));
      }
#pragma unroll
      for (int m = 0; m < 2; ++m)
#pragma unroll
        for (int n = 0; n < 8; ++n)
          acc[m][n] = __builtin_amdgcn_mfma_f32_16x16x32_bf16(
              af[m][kh * 4 + ks], bv[n], acc[m][n], 0, 0, 0);
    }

    if (kh == 1) {  // bt complete: epilogue
      const int bt = half * 8 + (ci >> 1);
      float cc[8], mincc = 3.4e38f;
#pragma unroll
      for (int n = 0; n < 8; ++n) {
        cc[n] = sqall[bt * 128 + n * 16 + lrow];
        mincc = fminf(mincc, cc[n]);
      }
      float maxg = -3.4e38f;
#pragma unroll
      for (int m = 0; m < 2; ++m)
#pragma unroll
        for (int n = 0; n < 8; ++n)
#pragma unroll
          for (int j = 0; j < 4; ++j) maxg = fmaxf(maxg, acc[m][n][j]);

      if (minrr + mincc - 2.f * maxg > thresh) {
        // every exp(w0) rounds to exactly 1.0f
#pragma unroll
        for (int m = 0; m < 2; ++m)
#pragma unroll
          for (int j = 0; j < 4; ++j) prs[m][j] += 8.0f;
      } else {
#pragma unroll
        for (int m = 0; m < 2; ++m)
#pragma unroll
          for (int j = 0; j < 4; ++j) {
#pragma unroll
            for (int n = 0; n < 8; ++n) {
              float d2 = fmaxf(fmaf(-2.f, acc[m][n][j], rr[m][j] + cc[n]), 0.f);
              if (d2 < thresh) {
                float e = __expf(__expf(nal * d2));
                prs[m][j] += e;
                u32 idx = atomicAdd(counter, 1u);
                if (idx < CAP) {
                  int srow = rowbase + wid * 32 + m * 16 + lq * 4 + j;
                  int tcol = bt * 128 + n * 16 + lrow;
                  records[2 * idx] = ((u32)b << 22) | ((u32)srow << 11) | (u32)tcol;
                  records[2 * idx + 1] = __builtin_bit_cast(u32, e);
                }
              } else {
                prs[m][j] += 1.0f;
              }
            }
          }
      }
      // reset acc for next bt
#pragma unroll
      for (int m = 0; m < 2; ++m)
#pragma unroll
        for (int n = 0; n < 8; ++n) acc[m][n] = (f32x4){0.f, 0.f, 0.f, 0.f};
    }
    __syncthreads();
  }

  // reduce prs across lrow group -> plain stores (no atomics)
#pragma unroll
  for (int m = 0; m < 2; ++m)
#pragma unroll
    for (int j = 0; j < 4; ++j) {
      float v = prs[m][j];
      v += __shfl_xor(v, 1);
      v += __shfl_xor(v, 2);
      v += __shfl_xor(v, 4);
      v += __shfl_xor(v, 8);
      if (lrow == 0)
        rpart[(size_t)(b * 2 + half) * NS + rowbase + wid * 32 + m * 16 +
              lq * 4 + j] = v;
    }
}

// ---------- rtot: r = h0+h1; cws[b,t] = sum_s 1/r[s] (baseline) ----------
__global__ __launch_bounds__(256) void rtot_kernel(const float* __restrict__ rpart,
                                                   float* __restrict__ cws) {
  __shared__ float ws4[4];
  const int b = blockIdx.x, tid = threadIdx.x, lane = tid & 63;
  float local = 0.f;
#pragma unroll
  for (int k = 0; k < 8; ++k) {
    int row = k * 256 + tid;
    float r = rpart[(size_t)(b * 2) * NS + row] +
              rpart[(size_t)(b * 2 + 1) * NS + row];
    local += 1.0f / r;
  }
#pragma unroll
  for (int off = 32; off; off >>= 1) local += __shfl_xor(local, off);
  if (lane == 0) ws4[tid >> 6] = local;
  __syncthreads();
  float tot = ws4[0] + ws4[1] + ws4[2] + ws4[3];
#pragma unroll
  for (int k = 0; k < 8; ++k) cws[(size_t)b * NS + k * 256 + tid] = tot;
}

// ---------- corr: apply sparse (exp(w0)-1)/r corrections ----------
__global__ __launch_bounds__(256) void corr_kernel(const u32* __restrict__ counter,
                                                   const u32* __restrict__ records,
                                                   const float* __restrict__ rpart,
                                                   float* __restrict__ cws) {
  u32 cnt = *counter;
  if (cnt > CAP) cnt = CAP;
  for (u32 i = blockIdx.x * 256 + threadIdx.x; i < cnt; i += gridDim.x * 256) {
    u32 meta = records[2 * i];
    float e = __builtin_bit_cast(float, records[2 * i + 1]);
    int b = meta >> 22, s = (meta >> 11) & 2047, t = meta & 2047;
    float r = rpart[(size_t)(b * 2) * NS + s] +
              rpart[(size_t)(b * 2 + 1) * NS + s];
    atomicAdd(&cws[(size_t)b * NS + t], (e - 1.0f) / r);
  }
}

// ---------- pooled[b,e] = (1/S) sum_t c[b,t] x[b,t,e] ----------
__global__ __launch_bounds__(256) void pooled_kernel(const short* __restrict__ xbf,
                                                     const float* __restrict__ cws,
                                                     float* __restrict__ pooled) {
  __shared__ float red[8 * 256];
  const int b = blockIdx.y;
  const int t0 = blockIdx.x * 128;
  const short* xb = xbf + ((size_t)b * NS + t0) * NE;
  const float* cb = cws + (size_t)b * NS + t0;
  const int g = threadIdx.x >> 5;
  const int e8 = (threadIdx.x & 31) * 8;
  float acc[8] = {0.f, 0.f, 0.f, 0.f, 0.f, 0.f, 0.f, 0.f};
#pragma unroll 4
  for (int t = g; t < 128; t += 8) {
    float cv = cb[t];
    s16x8 v = *(const s16x8*)(xb + (size_t)t * NE + e8);
#pragma unroll
    for (int j = 0; j < 8; ++j) acc[j] = fmaf(cv, bf16f(v[j]), acc[j]);
  }
#pragma unroll
  for (int j = 0; j < 8; ++j) red[g * 256 + e8 + j] = acc[j];
  __syncthreads();
  float s = 0.f;
#pragma unroll
  for (int g2 = 0; g2 < 8; ++g2) s += red[g2 * 256 + threadIdx.x];
  atomicAdd(&pooled[b * NE + threadIdx.x], s * (1.0f / NS));
}

// ---------- out[b,o] = pooled[b,:] . W[o,:] + bias[o] ----------
__global__ __launch_bounds__(256) void out_kernel(const float* __restrict__ pooled,
                                                  const float* __restrict__ W,
                                                  const float* __restrict__ bias,
                                                  float* __restrict__ out) {
  __shared__ float pl[NE];
  int b = blockIdx.x, o = threadIdx.x;
  pl[o] = pooled[b * NE + o];
  __syncthreads();
  const f32x4* wr4 = (const f32x4*)(W + (size_t)o * NE);
  float acc = bias[o];
#pragma unroll 8
  for (int e = 0; e < 64; ++e) {
    f32x4 w4 = wr4[e];
    acc += pl[e * 4 + 0] * w4.x + pl[e * 4 + 1] * w4.y + pl[e * 4 + 2] * w4.z +
           pl[e * 4 + 3] * w4.w;
  }
  out[b * NOUT + o] = acc;
}

extern "C" void kernel_launch(void* const* d_in, const int* in_sizes, int n_in,
                              void* d_out, int out_size, void* d_ws, size_t ws_size,
                              hipStream_t stream) {
  const float* x = (const float*)d_in[0];
  const float* alpha = (const float*)d_in[1];
  const float* W = (const float*)d_in[2];
  const float* bias = (const float*)d_in[3];
  float* out = (float*)d_out;

  float* pooled = (float*)d_ws;                 // NB*NE
  u32* counter = (u32*)(pooled + NB * NE);      // 1 (+31 pad)
  float* sq = (float*)(counter + 32);           // NB*NS
  float* rpart = sq + NB * NS;                  // 2*NB*NS
  float* cws = rpart + 2 * NB * NS;             // NB*NS
  u32* records = (u32*)(cws + NB * NS);         // 2*CAP
  short* xbf = (short*)(records + 2 * CAP);     // NB*NS*NE bf16

  // zero pooled + counter (contiguous region)
  hipMemsetAsync(pooled, 0, (size_t)NB * NE * sizeof(float) + 128, stream);

  prep_kernel<<<NB * NS / 4, 256, 0, stream>>>(x, xbf, sq);
  gram<<<512, 256, 0, stream>>>(xbf, sq, alpha, rpart, counter, records);
  rtot_kernel<<<NB, 256, 0, stream>>>(rpart, cws);
  corr_kernel<<<32, 256, 0, stream>>>(counter, records, rpart, cws);
  pooled_kernel<<<dim3(16, NB), 256, 0, stream>>>(xbf, cws, pooled);
  out_kernel<<<NB, 256, 0, stream>>>(pooled, W, bias, out);
}